// Round 7
// baseline (470.994 us; speedup 1.0000x reference)
//
#include <hip/hip_runtime.h>

// DeepseekV3MoE on MI355X (gfx950), bf16-MFMA, round 11.
// R6 state: 470us. Top dispatch front_kernel 112us @ 1.65TB/s (20% HBM,
// VALU 7%, Mfma 0) — streaming kernel 2.8x off roofline; transpose writes
// are 128B-per-4KB-row scatter and only 4 loads of per-thread ILP.
// Round-11: tcast tile 64x64 -> 128x64:
//   - 8 float4 loads/thread (2x ILP), reads stay 256B-coalesced
//   - writes remapped: 16 lanes per dest row -> 256B contiguous segments
//   - LDS 33KB/block (4 blocks/CU); tile reads 4-way aliased (non-critical)
//   - front 12321->7201 blocks, back 5120->2560
// Everything else identical to R10 (GEMM pipeline, assign-scan, zmeta, no
// hipMemsetAsync — that was the container-killer).

typedef unsigned short u16;
typedef unsigned int   u32;
typedef __bf16 bf16x8 __attribute__((ext_vector_type(8)));
typedef float  f32x4  __attribute__((ext_vector_type(4)));

#define T_TOK 2048
#define HDIM  2048
#define IDIM  1024
#define NEXP  8
#define ISDIM 2048
#define MAXROWS   5760   // fused path: 192-padded, worst 4096+8*191=5624 -> 30 tiles
#define MAXROWS_FB 5120  // fallback path: 128-padded

__device__ __forceinline__ u16 f2bf(float f) {
  u32 x = __float_as_uint(f);
  return (u16)((x + 0x7FFFu + ((x >> 16) & 1u)) >> 16);
}
__device__ __forceinline__ float bf2f(u16 v) { return __uint_as_float(((u32)v) << 16); }

#define GLL(g, l)                                                              \
  __builtin_amdgcn_global_load_lds(                                            \
      (const __attribute__((address_space(1))) void*)(g),                      \
      (__attribute__((address_space(3))) void*)(l), 16, 0, 0)

// ---------------- zmeta: zero meta[0..63] ----------------
__global__ void zmeta_kernel(int* __restrict__ meta) { meta[threadIdx.x] = 0; }

// ---------------- init (fallback path) ----------------
__global__ void init_kernel(int* __restrict__ perm, int* __restrict__ meta,
                            int* __restrict__ zrow) {
  int idx = blockIdx.x * 256 + threadIdx.x;
  if (idx < 8192) perm[idx] = -1;
  if (idx < 32) meta[idx] = 0;
  if (idx < 1024) zrow[idx] = 0;
}

// ---------------- transpose-cast tile core: 128 rows x 64 cols ----------------
// in fp32 [*][C], out bf16 [colmap][R]; ilv: out-row = (c>>4)*32+(c&15)+uoff
// Reads: 8 float4/thread, 256B segments. Writes: 16 lanes cover one dest row
// -> 256B contiguous per row, 4 rows/wave/iter.
__device__ __forceinline__ void tcast_tile2(const float* __restrict__ in,
                                            u16* __restrict__ out, int R, int C,
                                            int r0, int c0, int ilv, int uoff) {
  __shared__ float tile[128 * 65];
  int t = threadIdx.x;
  int i = t >> 4, j4 = t & 15;
#pragma unroll
  for (int ii = 0; ii < 8; ii++) {
    int r = i + ii * 16;  // 0..127
    float4 v = *(const float4*)(in + (long)(r0 + r) * C + c0 + j4 * 4);
    tile[r * 65 + j4 * 4 + 0] = v.x;
    tile[r * 65 + j4 * 4 + 1] = v.y;
    tile[r * 65 + j4 * 4 + 2] = v.z;
    tile[r * 65 + j4 * 4 + 3] = v.w;
  }
  __syncthreads();
  const int cc = t >> 4, ch = t & 15;  // cc 0..15, chunk ch 0..15
  const int rr = ch * 8;               // u16 offset 0..120
#pragma unroll
  for (int ph = 0; ph < 4; ph++) {
    int c = cc + ph * 16;  // dest row 0..63
    u16 e[8];
#pragma unroll
    for (int u = 0; u < 8; u++) e[u] = f2bf(tile[(rr + u) * 65 + c]);
    uint4 w;
    w.x = (u32)e[0] | ((u32)e[1] << 16);
    w.y = (u32)e[2] | ((u32)e[3] << 16);
    w.z = (u32)e[4] | ((u32)e[5] << 16);
    w.w = (u32)e[6] | ((u32)e[7] << 16);
    int cg = c0 + c;
    int orow = ilv ? ((cg >> 4) << 5) + (cg & 15) + uoff : cg;
    *(uint4*)(out + (long)orow * R + r0 + rr) = w;
  }
}

// ---------------- gate core (no fences; atomics only) ----------------
template <bool ZERO_OUT>
__device__ __forceinline__ void gate_core(const float* __restrict__ x,
                                          const float* __restrict__ gw,
                                          u16* __restrict__ xb,
                                          float* __restrict__ outz,
                                          float* __restrict__ topw,
                                          int* __restrict__ topi,
                                          int* __restrict__ meta, int t) {
  const int tid = threadIdx.x;
  const long o = (long)t * HDIM + tid * 8;
  float4 a = *(const float4*)(x + o);
  float4 b = *(const float4*)(x + o + 4);
  if constexpr (ZERO_OUT) {
    float4 z = {0.f, 0.f, 0.f, 0.f};
    *(float4*)(outz + o) = z;
    *(float4*)(outz + o + 4) = z;
  }
  uint4 w;
  w.x = (u32)f2bf(a.x) | ((u32)f2bf(a.y) << 16);
  w.y = (u32)f2bf(a.z) | ((u32)f2bf(a.w) << 16);
  w.z = (u32)f2bf(b.x) | ((u32)f2bf(b.y) << 16);
  w.w = (u32)f2bf(b.z) | ((u32)f2bf(b.w) << 16);
  *(uint4*)(xb + o) = w;
  float acc[NEXP];
#pragma unroll
  for (int e = 0; e < NEXP; e++) {
    const float* gr = gw + e * HDIM + tid * 8;
    float4 wa = *(const float4*)gr;
    float4 wb = *(const float4*)(gr + 4);
    acc[e] = a.x * wa.x + a.y * wa.y + a.z * wa.z + a.w * wa.w +
             b.x * wb.x + b.y * wb.y + b.z * wb.z + b.w * wb.w;
  }
#pragma unroll
  for (int off = 32; off; off >>= 1)
#pragma unroll
    for (int e = 0; e < NEXP; e++) acc[e] += __shfl_down(acc[e], off, 64);
  __shared__ float red[4][NEXP];
  if ((tid & 63) == 0) {
#pragma unroll
    for (int e = 0; e < NEXP; e++) red[tid >> 6][e] = acc[e];
  }
  __syncthreads();
  if (tid == 0) {
    float s[NEXP];
#pragma unroll
    for (int e = 0; e < NEXP; e++) s[e] = red[0][e] + red[1][e] + red[2][e] + red[3][e];
    int i0 = 0;
#pragma unroll
    for (int e = 1; e < NEXP; e++)
      if (s[e] > s[i0]) i0 = e;
    int i1 = -1;
#pragma unroll
    for (int e = 0; e < NEXP; e++) {
      if (e == i0) continue;
      if (i1 < 0 || s[e] > s[i1]) i1 = e;
    }
    float w0 = 1.f / (1.f + __expf(s[i1] - s[i0]));  // softmax->top2->renorm
    topw[t * 2 + 0] = w0;
    topw[t * 2 + 1] = 1.f - w0;
    topi[t * 2 + 0] = i0;
    topi[t * 2 + 1] = i1;
    atomicAdd(meta + i0, 1);
    atomicAdd(meta + i1, 1);
  }
}

// ---- front: gate (2048) + wgu tcast (4096) + sgsu tcast (1024) + init (33) ----
// meta must be zeroed (zmeta_kernel) BEFORE this kernel.
__global__ __launch_bounds__(256) void front_kernel(
    const float* __restrict__ x, const float* __restrict__ gw,
    const float* __restrict__ wg, const float* __restrict__ wu,
    const float* __restrict__ sg, const float* __restrict__ su,
    u16* __restrict__ xb, float* __restrict__ topw, int* __restrict__ topi,
    u16* __restrict__ wguT, u16* __restrict__ sgsuT, int* __restrict__ perm,
    int* __restrict__ meta, int* __restrict__ zrow) {
  int b = blockIdx.x;
  if (b < 2048) {  // gate part
    gate_core<false>(x, gw, xb, nullptr, topw, topi, meta, b);
    return;
  }
  b -= 2048;
  if (b < 4096) {  // wgu: z<8 wg / z>=8 wu, 256 blocks per z (y16 x16)
    int z = b >> 8, rem = b & 255, y = rem >> 4, xk = rem & 15;
    int isU = z >= 8 ? 1 : 0;
    int e = isU ? z - 8 : z;
    const float* in = (isU ? wu : wg) + (long)e * HDIM * IDIM;
    u16* o = wguT + (long)e * 2 * IDIM * HDIM;
    tcast_tile2(in, o, HDIM, IDIM, y * 128, xk * 64, 1, isU ? 16 : 0);
    return;
  }
  b -= 4096;
  if (b < 1024) {  // sgsu: 512 blocks per z (y16 x32)
    int z = b >> 9, rem = b & 511, y = rem >> 5, xk = rem & 31;
    const float* in = z ? su : sg;
    tcast_tile2(in, sgsuT, HDIM, ISDIM, y * 128, xk * 64, 1, z ? 16 : 0);
    return;
  }
  b -= 1024;  // init part: 33 blocks
  int idx = b * 256 + threadIdx.x;
  if (idx < 8192) perm[idx] = -1;
  if (b == 32) {
#pragma unroll
    for (int k = 0; k < 4; k++) zrow[threadIdx.x * 4 + k] = 0;
  }
}

// ---- back: sd (512 blk) + wd (2048 blk) plain tcast, one launch ----
__global__ __launch_bounds__(256) void tcast_back(const float* __restrict__ sd,
                                                  const float* __restrict__ wd,
                                                  u16* __restrict__ sdT,
                                                  u16* __restrict__ wdT) {
  int b = blockIdx.x;
  if (b < 512) {  // sd [IS][H] -> sdT [H][IS]: y16 x32
    int y = b >> 5, xk = b & 31;
    tcast_tile2(sd, sdT, ISDIM, HDIM, y * 128, xk * 64, 0, 0);
  } else {  // wd [e][I][H] -> wdT [e][H][I], 256 per z (y8 x32)
    int b2 = b - 512;
    int z = b2 >> 8, rem = b2 & 255, y = rem >> 5, xk = rem & 31;
    tcast_tile2(wd + (long)z * IDIM * HDIM, wdT + (long)z * HDIM * IDIM, IDIM, HDIM,
                y * 128, xk * 64, 0, 0);
  }
}

// ---------------- gate (fallback path: zeroes out, no scan) ----------------
__global__ __launch_bounds__(256) void gate_kernel(
    const float* __restrict__ x, const float* __restrict__ gw,
    u16* __restrict__ xb, float* __restrict__ outz,
    float* __restrict__ topw, int* __restrict__ topi, int* __restrict__ meta) {
  gate_core<true>(x, gw, xb, outz, topw, topi, meta, blockIdx.x);
}

// ---------------- scan (fallback path) ----------------
__global__ void scan_kernel(int* __restrict__ meta, int pad) {
  if (threadIdx.x == 0 && blockIdx.x == 0) {
    int o = 0;
    meta[16] = 0;
#pragma unroll
    for (int e = 0; e < NEXP; e++) {
      o += ((meta[e] + pad - 1) / pad) * pad;
      meta[17 + e] = o;
    }
  }
}

// ---------------- assign: perm[row]=t*2+slot, tokrow[t*2+slot]=row ----------------
__global__ void assign_kernel(const int* __restrict__ topi, int* __restrict__ meta,
                              int* __restrict__ perm, int* __restrict__ tokrow,
                              int pad) {
  __shared__ int offs[9];
  if (pad > 0) {
    if (threadIdx.x == 0) {
      int o = 0;
      offs[0] = 0;
#pragma unroll
      for (int e = 0; e < NEXP; e++) {
        o += ((meta[e] + pad - 1) / pad) * pad;
        offs[e + 1] = o;
      }
    }
    __syncthreads();
    if (blockIdx.x == 0 && threadIdx.x < 9) meta[16 + threadIdx.x] = offs[threadIdx.x];
  } else {
    if (threadIdx.x < 9) offs[threadIdx.x] = meta[16 + threadIdx.x];
    __syncthreads();
  }
  int idx = blockIdx.x * 256 + threadIdx.x;  // < 4096
  int e = topi[idx];
  int pos = atomicAdd(meta + 8 + e, 1);
  int row = offs[e] + pos;
  perm[row] = idx;
  tokrow[idx] = row;
}

// ---------------- legacy blockIdx-based tcast (fallback path) ----------------
__global__ __launch_bounds__(256) void tcast_kernel(const float* __restrict__ in,
                                                    u16* __restrict__ out, int R, int C,
                                                    long inz, long outz) {
  tcast_tile2(in + (long)blockIdx.z * inz, out + (long)blockIdx.z * outz, R, C,
              blockIdx.y * 128, blockIdx.x * 64, 0, 0);
}

// ---------------- silu-mul in place (fallback path) ----------------
template <int HALF8>  // half-width / 8
__device__ __forceinline__ void silu_do(u16* __restrict__ buf, long i) {
  long r = i / HALF8, c = i % HALF8;
  u16* g = buf + r * (long)HALF8 * 16 + c * 8;
  uint4 gv = *(const uint4*)g;
  uint4 uv = *(const uint4*)(g + HALF8 * 8);
  const u32* gp = &gv.x;
  const u32* up = &uv.x;
  uint4 w;
  u32* wp = &w.x;
#pragma unroll
  for (int j = 0; j < 4; j++) {
    float g0 = bf2f((u16)(gp[j] & 0xFFFF)), g1 = bf2f((u16)(gp[j] >> 16));
    float u0 = bf2f((u16)(up[j] & 0xFFFF)), u1 = bf2f((u16)(up[j] >> 16));
    float r0 = g0 / (1.f + __expf(-g0)) * u0;
    float r1 = g1 / (1.f + __expf(-g1)) * u1;
    wp[j] = (u32)f2bf(r0) | ((u32)f2bf(r1) << 16);
  }
  *(uint4*)g = w;
}
template <int HALF8>
__global__ void silu_kernel(u16* __restrict__ buf) {
  long i = (long)blockIdx.x * 256 + threadIdx.x;
  silu_do<HALF8>(buf, i);
}

// ================= phase-interleaved GEMM body (R3, proven) =================
// BM = MI*32 x BN=256, BK=32, 512 threads = 8 waves (2M x 4N), wave (MI*16)x64.
// LDS: 3 buffers x [A 256x32 | B 256x32] = 3x16384 u16 = 96KB. Stage tile t+2
// during tile t (4 GLL: A0,A1 ph1; B0,B1 ph2); end-of-tile s_waitcnt vmcnt(4)
// (outstanding = t+2's 4 -> t+1's landed, in-order); s_barrier publishes.
// Chunk-XOR swizzle slot = kc ^ ((row>>1)&3): ds_read_b128 conflict-free.
// EPI: 0 = plain bf16, 1 = plain fp32, 2 = silu-pair bf16 (B cols interleaved
// g|u at 16-granularity; acc[ni],acc[ni+1] = g,u of same 16 logical cols).
template <int EPI, int MI, bool PERMA, bool SEGB>
__device__ __forceinline__ void gemm_body3(
    int mt, int nt, u16* lds, const u16* __restrict__ A, long lda,
    const u16* __restrict__ B, long ldbz, int K, u16* __restrict__ Cb,
    float* __restrict__ Cf, long ldc, const int* __restrict__ offp,
    const int* __restrict__ perm, const u16* __restrict__ zrow) {
  const int row0 = mt * (MI * 32);
  if constexpr (SEGB) {
    if (row0 >= offp[8]) return;
    int e = 0;
    while (offp[e + 1] <= row0) ++e;
    B += (long)e * ldbz;
  }
  const int tid = threadIdx.x;

  // ---- staging sources (pre-swizzled chunk; LDS dest linear) ----
  const int ra = tid >> 2, sa = tid & 3;
  const int swz0 = (sa ^ ((ra >> 1) & 3)) * 8;
  const u16 *gA0, *gA1;
  if constexpr (PERMA) {
    int p0 = perm[row0 + ra];
    int p1 = perm[row0 + 128 + ra];
    gA0 = ((p0 < 0) ? zrow : A + (long)(p0 >> 1) * lda) + swz0;
    gA1 = ((p1 < 0) ? zrow : A + (long)(p1 >> 1) * lda) + swz0;
  } else {
    gA0 = A + (long)(row0 + ra) * lda + swz0;
    gA1 = A + (long)(row0 + 128 + ra) * lda + swz0;
  }
  const u16* gB0 = B + (long)(nt * 256 + ra) * K + swz0;
  const u16* gB1 = B + (long)(nt * 256 + 128 + ra) * K + swz0;

  // ---- fragment read offsets (u16 elements within one buffer) ----
  const int lane = tid & 63, w = tid >> 6;
  const int wm = (w >> 2) * (MI * 16), wn = (w & 3) * 64;
  const int lrow = lane & 15, kc = lane >> 4;
  int offA[MI], offB[4];
#pragma unroll
  for (int i = 0; i < MI; i++) {
    int r = wm + i * 16 + lrow;
    offA[i] = r * 32 + ((kc ^ ((r >> 1) & 3)) << 3);
  }
#pragma unroll
  for (int i = 0; i < 4; i++) {
    int r = wn + i * 16 + lrow;
    offB[i] = 8192 + r * 32 + ((kc ^ ((r >> 1) & 3)) << 3);
  }

  f32x4 acc[MI][4];
#pragma unroll
  for (int i = 0; i < MI; i++)
#pragma unroll
    for (int j = 0; j < 4; j++) acc[i][j] = f32x4{0.f, 0.f, 0.f, 0.f};

  const int nk = K >> 5;
  // prologue: stage tiles 0 and 1 (8 loads), wait for tile 0 (leave tile 1's 4)
  {
    u16* b0 = lds;
    GLL(gA0, b0 + tid * 8);
    GLL(gA1, b0 + 4096 + tid * 8);
    GLL(gB0, b0 + 8192 + tid * 8);
    GLL(gB1, b0 + 12288 + tid * 8);
    u16* b1 = lds + 16384;
    GLL(gA0 + 32, b1 + tid * 8);
    GLL(gA1 + 32, b1 + 4096 + tid * 8);
    GLL(gB0 + 32, b1 + 8192 + tid * 8);
    GLL(gB1 + 32, b1 + 12288 + tid * 8);
  }
  asm volatile("s_waitcnt vmcnt(4)" ::: "memory");
  asm volatile("s_barrier" ::: "memory");

  constexpr int MH = MI / 2;
  int cur = 0, stg = 2;
  for (int t = 0; t < nk; ++t) {
    int t2 = t + 2;
    if (t2 >= nk) t2 -= nk;  // tail: wrap-stage into dead buffer (drained at end)
    const int kk2 = t2 * 32;
    u16* buf = lds + cur * 16384;
    u16* sb = lds + stg * 16384;

    // ---- phase 1: read A[mi<MH] + B; stage A(t+2); MFMA quad 1 ----
    bf16x8 af[MH], bfv[4];
#pragma unroll
    for (int i = 0; i < MH; i++) af[i] = *(const bf16x8*)(buf + offA[i]);
#pragma unroll
    for (int i = 0; i < 4; i++) bfv[i] = *(const bf16x8*)(buf + offB[i]);
    GLL(gA0 + kk2, sb + tid * 8);
    GLL(gA1 + kk2, sb + 4096 + tid * 8);
    asm volatile("s_barrier" ::: "memory");
    __builtin_amdgcn_s_setprio(1);
#pragma unroll
    for (int mi = 0; mi < MH; mi++)
#pragma unroll
      for (int ni = 0; ni < 4; ni++)
        acc[mi][ni] = __builtin_amdgcn_mfma_f32_16x16x32_bf16(af[mi], bfv[ni],
                                                              acc[mi][ni], 0, 0, 0);
    __builtin_amdgcn_s_setprio(0);
    asm volatile("s_barrier" ::: "memory");

    // ---- phase 2: read A[mi>=MH]; stage B(t+2); MFMA quad 2 ----
    bf16x8 ag[MI - MH];
#pragma unroll
    for (int i = 0; i < MI - MH; i++) ag[i] = *(const bf16x8*)(buf + offA[MH + i]);
    GLL(gB0 + kk2, sb + 8192 + tid * 8);
    GLL(gB1 + kk2, sb + 12288 + tid * 8);
    asm volatile("s_barrier" ::: "memory");
    __builtin_amdgcn_s_setprio(1);
#pragma unroll
    for (int mi = 0; mi < MI - MH; mi++)
#pragma unroll
      for (int ni = 0; ni < 4; ni++)
        acc[MH + mi][ni] = __builtin_amdgcn_mfma_f32_16x16x32_bf16(
            ag[mi], bfv[ni], acc[MH + mi][ni], 0, 0, 0);
    __builtin_amdgcn_s_setprio(0);
    asm volatile("s_waitcnt vmcnt(4)" ::: "memory");
    asm volatile("s_barrier" ::: "memory");
    cur = (cur == 2) ? 0 : cur + 1;
    stg = (stg == 2) ? 0 : stg + 1;
  }
  asm volatile("s_waitcnt vmcnt(0)" ::: "memory");

  // C/D layout: col = lane&15, row = (lane>>4)*4 + reg   [measured m89/m91]
  const int crow = row0 + wm + ((lane >> 4) << 2);
#pragma unroll
  for (int mi = 0; mi < MI; mi++) {
    if constexpr (EPI == 2) {
      // logical col = nt*128 + wn/2 + nh*16 + (lane&15); pair (2nh, 2nh+1)=(g,u)
      const int ccl = nt * 128 + (wn >> 1) + (lane & 15);
#pragma unroll
      for (int nh = 0; nh < 2; nh++) {
        f32x4 g = acc[mi][nh * 2], u = acc[mi][nh * 2 + 1];
#pragma unroll
        for (int r = 0; r < 4; r++) {
          float gg = g[r];
          float h = gg / (1.f + __expf(-gg)) * u[r];
          Cb[(long)(crow + mi * 16 + r) * ldc + ccl + nh * 16] = f2bf(h);
        }
      }
    } else {
      const int ccol = nt * 256 + wn + (lane & 15);
#pragma unroll
      for (int ni = 0; ni < 4; ni++) {
#pragma unroll
        for (int r = 0; r < 4; r++) {
          int row = crow + mi * 16 + r;
          int col = ccol + ni * 16;
          float v = acc[mi][ni][r];
          if constexpr (EPI == 0) {
            Cb[(long)row * ldc + col] = f2bf(v);
          } else {
            Cf[(long)row * ldc + col] = v;
          }
        }
      }
    }
  }
}

// ---- fused [shared gu (128, BM=256) | routed gu (240, BM=192)], silu epilogue ----
__global__ __launch_bounds__(512, 2) void gemm_gu_fused(
    const u16* __restrict__ xb, const u16* __restrict__ wguT,
    const u16* __restrict__ sgsuT, u16* __restrict__ gur, u16* __restrict__ gus,
    const int* __restrict__ offp, const int* __restrict__ perm,
    const u16* __restrict__ zrow) {
  __shared__ __align__(16) u16 lds3[49152];
  int bid = blockIdx.x;
  if (bid < 128) {
    gemm_body3<2, 8, false, false>(bid >> 4, bid & 15, lds3, xb, HDIM, sgsuT, 0, HDIM,
                                   gus, nullptr, ISDIM, nullptr, nullptr, nullptr);
  } else {
    int b = bid - 128;  // mt 0..29, nt 0..7
    gemm_body3<2, 6, true, true>(b >> 3, b & 7, lds3, xb, HDIM, wguT,
                                 (long)2 * IDIM * HDIM, HDIM, gur, nullptr, IDIM,
                                 offp, perm, zrow);
  }
}

// ---- fused [shared down fp32 (64, BM=256) | routed down bf16->eo (240, BM=192)] ----
__global__ __launch_bounds__(512, 2) void gemm_down_plain(
    const u16* __restrict__ gus, const u16* __restrict__ sdT,
    const u16* __restrict__ gur, const u16* __restrict__ wdT, float* __restrict__ out,
    u16* __restrict__ eo, const int* __restrict__ offp) {
  __shared__ __align__(16) u16 lds3[49152];
  int bid = blockIdx.x;
  if (bid < 64) {
    gemm_body3<1, 8, false, false>(bid >> 3, bid & 7, lds3, gus, ISDIM, sdT, 0,
                                   ISDIM, nullptr, out, HDIM, nullptr, nullptr, nullptr);
  } else {
    int b = bid - 64;  // mt 0..29, nt 0..7
    gemm_body3<0, 6, false, true>(b >> 3, b & 7, lds3, gur, IDIM, wdT,
                                  (long)HDIM * IDIM, IDIM, eo, nullptr, HDIM, offp,
                                  nullptr, nullptr);
  }
}

// ---- combine: out[t] += w0*eo[r0] + w1*eo[r1] ----
__global__ __launch_bounds__(256) void combine_kernel(float* __restrict__ out,
                                                      const u16* __restrict__ eo,
                                                      const int* __restrict__ tokrow,
                                                      const float* __restrict__ topw) {
  const int t = blockIdx.x, tid = threadIdx.x;
  const long o = (long)t * HDIM + tid * 8;
  const int r0 = tokrow[t * 2], r1 = tokrow[t * 2 + 1];
  const float w0 = topw[t * 2], w1 = topw[t * 2 + 1];
  float4 a = *(const float4*)(out + o);
  float4 b = *(const float4*)(out + o + 4);
  uint4 e0 = *(const uint4*)(eo + (long)r0 * HDIM + tid * 8);
  uint4 e1 = *(const uint4*)(eo + (long)r1 * HDIM + tid * 8);
  const u32* p0 = &e0.x;
  const u32* p1 = &e1.x;
  float r[8] = {a.x, a.y, a.z, a.w, b.x, b.y, b.z, b.w};
#pragma unroll
  for (int j = 0; j < 4; j++) {
    r[j * 2 + 0] += w0 * bf2f((u16)(p0[j] & 0xFFFF)) + w1 * bf2f((u16)(p1[j] & 0xFFFF));
    r[j * 2 + 1] += w0 * bf2f((u16)(p0[j] >> 16)) + w1 * bf2f((u16)(p1[j] >> 16));
  }
  float4 oa = {r[0], r[1], r[2], r[3]};
  float4 ob = {r[4], r[5], r[6], r[7]};
  *(float4*)(out + o) = oa;
  *(float4*)(out + o + 4) = ob;
}

// ======== legacy 128x128 body (fallback path only, 128-padded segments) ========
template <int CMODE, bool PERMA, bool SEGB>
__device__ __forceinline__ void gemm_body(
    int mt, int nt, u16* ldsA, u16* ldsB, const u16* __restrict__ A, long lda,
    const u16* __restrict__ B, long ldbz, int K, u16* __restrict__ Cb,
    float* __restrict__ Cf, long ldc, const int* __restrict__ offp,
    const int* __restrict__ perm, const float* __restrict__ topw,
    const u16* __restrict__ zrow) {
  const int row0 = mt * 128;
  if constexpr (SEGB) {
    if (row0 >= offp[8]) return;
    int e = 0;
    while (offp[e + 1] <= row0) ++e;
    B += (long)e * ldbz;
  }
  const int tid = threadIdx.x;
  const u16* gA[4];
  const u16* gB[4];
  u16 *lA[4], *lB[4];
#pragma unroll
  for (int j = 0; j < 4; j++) {
    int c = tid + 256 * j;
    int r = c >> 3, s = c & 7;
    int gk = (s ^ (r & 7)) * 8;
    const u16* arow;
    if constexpr (PERMA) {
      int p = perm[row0 + r];
      arow = (p < 0) ? zrow : A + (long)(p >> 1) * lda;
    } else {
      arow = A + (long)(row0 + r) * lda;
    }
    gA[j] = arow + gk;
    gB[j] = B + (long)(nt * 128 + r) * K + gk;
    lA[j] = ldsA + c * 8;
    lB[j] = ldsB + c * 8;
  }
  const int lane = tid & 63, wave = tid >> 6;
  const int wm = (wave & 1) * 64, wn = (wave >> 1) * 64;
  const int lrow = lane & 15;
  const int kchunk = lane >> 4;
  const int rsw = lrow & 7;

  f32x4 acc[4][4];
#pragma unroll
  for (int i = 0; i < 4; i++)
#pragma unroll
    for (int j = 0; j < 4; j++) acc[i][j] = f32x4{0.f, 0.f, 0.f, 0.f};

  const int nk = K >> 6;
  for (int kt = 0; kt < nk; ++kt) {
    const int kk = kt * 64;
#pragma unroll
    for (int j = 0; j < 4; j++) {
      GLL(gA[j] + kk, lA[j]);
      GLL(gB[j] + kk, lB[j]);
    }
    __syncthreads();
#pragma unroll
    for (int half = 0; half < 2; half++) {
      const int slot = (kchunk + half * 4) ^ rsw;
      bf16x8 af[4], bfv[4];
#pragma unroll
      for (int mi = 0; mi < 4; mi++)
        af[mi] = *(const bf16x8*)(ldsA + (wm + lrow + mi * 16) * 64 + slot * 8);
#pragma unroll
      for (int ni = 0; ni < 4; ni++)
        bfv[ni] = *(const bf16x8*)(ldsB + (wn + lrow + ni * 16) * 64 + slot * 8);
#pragma unroll
      for (int mi = 0; mi < 4; mi++)
#pragma unroll
        for (int ni = 0; ni < 4; ni++)
          acc[mi][ni] = __builtin_amdgcn_mfma_f32_16x16x32_bf16(af[mi], bfv[ni],
                                                                acc[mi][ni], 0, 0, 0);
    }
    __syncthreads();
  }

  const int crow = row0 + wm + ((lane >> 4) << 2);
  const int ccol = nt * 128 + wn + (lane & 15);
#pragma unroll
  for (int mi = 0; mi < 4; mi++) {
#pragma unroll
    for (int ni = 0; ni < 4; ni++) {
#pragma unroll
      for (int r = 0; r < 4; r++) {
        int row = crow + mi * 16 + r;
        int col = ccol + ni * 16;
        float v = acc[mi][ni][r];
        if constexpr (CMODE == 0) {
          Cb[(long)row * ldc + col] = f2bf(v);
        } else if constexpr (CMODE == 1) {
          Cf[(long)row * ldc + col] = v;
        } else if constexpr (CMODE == 2) {
          int p = perm[row];
          if (p >= 0) atomicAdd(Cf + (long)(p >> 1) * ldc + col, topw[p] * v);
        } else {
          atomicAdd(Cf + (long)row * ldc + col, v);
        }
      }
    }
  }
}

// ---- fallback kernels (small ws): atomic design, 128-padded ----
__global__ __launch_bounds__(256) void gemm_routed_gu(
    const u16* __restrict__ xb, const u16* __restrict__ wT, u16* __restrict__ Cb,
    const int* __restrict__ offp, const int* __restrict__ perm,
    const u16* __restrict__ zrow) {
  __shared__ __align__(16) u16 ldsA[8192], ldsB[8192];
  gemm_body<0, true, true>(blockIdx.y, blockIdx.x, ldsA, ldsB, xb, HDIM, wT,
                           (long)IDIM * HDIM, HDIM, Cb, nullptr, 2 * IDIM, offp, perm,
                           nullptr, zrow);
}
__global__ __launch_bounds__(256) void gemm_shared_gu(const u16* __restrict__ xb,
                                                      const u16* __restrict__ sgsuT,
                                                      u16* __restrict__ gus) {
  __shared__ __align__(16) u16 ldsA[8192], ldsB[8192];
  gemm_body<0, false, false>(blockIdx.y, blockIdx.x, ldsA, ldsB, xb, HDIM, sgsuT, 0, HDIM,
                             gus, nullptr, 2 * ISDIM, nullptr, nullptr, nullptr, nullptr);
}
__global__ __launch_bounds__(256) void gemm_down_atomic(
    const u16* __restrict__ gus, const u16* __restrict__ sdT,
    const u16* __restrict__ gur, const u16* __restrict__ wdT, float* __restrict__ out,
    const int* __restrict__ offp, const int* __restrict__ perm,
    const float* __restrict__ topw) {
  __shared__ __align__(16) u16 ldsA[8192], ldsB[8192];
  int bid = blockIdx.x;
  if (bid < 256) {
    gemm_body<3, false, false>(bid / 16, bid % 16, ldsA, ldsB, gus, 2 * ISDIM, sdT, 0,
                               ISDIM, nullptr, out, HDIM, nullptr, nullptr, nullptr,
                               nullptr);
  } else {
    int b = bid - 256;
    gemm_body<2, false, true>(b / 16, b % 16, ldsA, ldsB, gur, 2 * IDIM, wdT,
                              (long)HDIM * IDIM, IDIM, nullptr, out, HDIM, offp, perm,
                              topw, nullptr);
  }
}

extern "C" void kernel_launch(void* const* d_in, const int* in_sizes, int n_in,
                              void* d_out, int out_size, void* d_ws, size_t ws_size,
                              hipStream_t stream) {
  const float* x  = (const float*)d_in[0];
  const float* gw = (const float*)d_in[1];
  const float* wg = (const float*)d_in[2];
  const float* wu = (const float*)d_in[3];
  const float* wd = (const float*)d_in[4];
  const float* sg = (const float*)d_in[5];
  const float* su = (const float*)d_in[6];
  const float* sd = (const float*)d_in[7];
  float* out = (float*)d_out;

  char* ws = (char*)d_ws;
  size_t off = 0;
  auto alloc = [&](size_t b) {
    size_t o = off;
    off += (b + 255) & ~(size_t)255;
    return (void*)(ws + o);
  };
  u16*   xb     = (u16*)alloc((size_t)T_TOK * HDIM * 2);
  u16*   gur    = (u16*)alloc((size_t)MAXROWS * 2 * IDIM * 2);  // fused: hr in [MAXROWS][IDIM]
  u16*   gus    = (u16*)alloc((size_t)T_TOK * 2 * ISDIM * 2);   // fused: hs in [T_TOK][ISDIM]
  float* topw   = (float*)alloc((size_t)T_TOK * 2 * 4);
  int*   topi   = (int*)alloc((size_t)T_TOK * 2 * 4);
  int*   tokrow = (int*)alloc((size_t)T_TOK * 2 * 4);
  int*   perm   = (int*)alloc(8192 * 4);
  int*   meta   = (int*)alloc(64 * 4);
  u16*   zrow   = (u16*)alloc(4096);
  size_t base = off;

  const size_t SZ_WGUT  = (size_t)NEXP * 2 * IDIM * HDIM * 2;  // 64 MiB
  const size_t SZ_SGSUT = (size_t)2 * ISDIM * HDIM * 2;        // 16 MiB
  const size_t SZ_SDT   = (size_t)HDIM * ISDIM * 2;            // 8 MiB
  const size_t SZ_WDT   = (size_t)NEXP * HDIM * IDIM * 2;      // 32 MiB
  const bool fused = ws_size >= base + SZ_WGUT + SZ_SGSUT;

  if (fused) {
    u16* wguT  = (u16*)(ws + base);
    u16* sgsuT = (u16*)(ws + base + SZ_WGUT);
    u16* sdT   = wguT;                              // reuse after gu gemm
    u16* wdT   = wguT + SZ_SDT / 2;                 // elements
    u16* eo    = wguT + (SZ_SDT + SZ_WDT) / 2;      // 23.6 MiB in 24 MiB tail
    // 0: zero meta (tiny kernel; stream-ordered before front's gate atomics)
    zmeta_kernel<<<1, 64, 0, stream>>>(meta);
    // 1: gate + wgu/sgsu tcast + perm/zrow init (independent parts, one launch)
    front_kernel<<<7201, 256, 0, stream>>>(x, gw, wg, wu, sg, su, xb, topw, topi,
                                           wguT, sgsuT, perm, meta, (int*)zrow);
    // 2: assign (+local padded scan; publishes meta[16..24])
    assign_kernel<<<16, 256, 0, stream>>>(topi, meta, perm, tokrow, 192);
    // 3: gu GEMM with fused silu epilogue -> hr (gur), hs (gus)
    gemm_gu_fused<<<368, 512, 0, stream>>>(xb, wguT, sgsuT, gur, gus, meta + 16, perm,
                                           zrow);
    // 4: sd+wd tcast (into reused wgu region)
    tcast_back<<<2560, 256, 0, stream>>>(sd, wd, sdT, wdT);
    // 5: down GEMM (shared fp32 -> out, routed bf16 -> eo)
    gemm_down_plain<<<304, 512, 0, stream>>>(gus, sdT, gur, wdT, out, eo, meta + 16);
    // 6: combine
    combine_kernel<<<T_TOK, 256, 0, stream>>>(out, eo, tokrow, topw);
  } else {
    u16* wT    = (u16*)(ws + base);  // 40 MiB region, sequentially reused
    u16* sgsuT = wT;
    u16* sdT   = wT;
    u16* wdT   = wT + SZ_SDT / 2;
    init_kernel<<<32, 256, 0, stream>>>(perm, meta, (int*)zrow);
    gate_kernel<<<T_TOK, 256, 0, stream>>>(x, gw, xb, out, topw, topi, meta);
    scan_kernel<<<1, 64, 0, stream>>>(meta, 128);
    assign_kernel<<<16, 256, 0, stream>>>(topi, meta, perm, tokrow, 0);
    tcast_kernel<<<dim3(IDIM / 64, HDIM / 128, NEXP), 256, 0, stream>>>(
        wg, wT, HDIM, IDIM, (long)HDIM * IDIM, (long)IDIM * HDIM);
    gemm_routed_gu<<<dim3(8, MAXROWS_FB / 128), 256, 0, stream>>>(xb, wT, gur, meta + 16,
                                                                  perm, zrow);
    tcast_kernel<<<dim3(IDIM / 64, HDIM / 128, NEXP), 256, 0, stream>>>(
        wu, wT, HDIM, IDIM, (long)HDIM * IDIM, (long)IDIM * HDIM);
    gemm_routed_gu<<<dim3(8, MAXROWS_FB / 128), 256, 0, stream>>>(
        xb, wT, gur + IDIM, meta + 16, perm, zrow);
    silu_kernel<128><<<(MAXROWS_FB * IDIM / 8) / 256, 256, 0, stream>>>(gur);
    tcast_kernel<<<dim3(ISDIM / 64, HDIM / 128, 1), 256, 0, stream>>>(sg, sgsuT, HDIM,
                                                                      ISDIM, 0, 0);
    tcast_kernel<<<dim3(ISDIM / 64, HDIM / 128, 1), 256, 0, stream>>>(
        su, sgsuT + (size_t)ISDIM * HDIM, HDIM, ISDIM, 0, 0);
    gemm_shared_gu<<<dim3(32, 16), 256, 0, stream>>>(xb, sgsuT, gus);
    silu_kernel<256><<<(T_TOK * ISDIM / 8) / 256, 256, 0, stream>>>(gus);
    tcast_kernel<<<dim3(HDIM / 64, ISDIM / 128, 1), 256, 0, stream>>>(sd, sdT, ISDIM,
                                                                      HDIM, 0, 0);
    tcast_kernel<<<dim3(HDIM / 64, IDIM / 128, NEXP), 256, 0, stream>>>(
        wd, wdT, IDIM, HDIM, (long)IDIM * HDIM, (long)HDIM * IDIM);
    gemm_down_atomic<<<896, 256, 0, stream>>>(gus, sdT, gur, wdT, out, meta + 16, perm,
                                              topw);
  }
}

// Round 8
// 441.850 us; speedup vs baseline: 1.0660x; 1.0660x over previous
//
#include <hip/hip_runtime.h>

// DeepseekV3MoE on MI355X (gfx950), bf16-MFMA, round 12.
// R7 null: front tile rework (64x64 -> 128x64) changed nothing — front is
// latency/structure-bound (no pipe >7%, HBM 20%, L3-warm). Stop micro-tuning;
// restructure:
//   - gate loses its meta atomics; zmeta + assign replaced by ONE single-block
//     assign1 (LDS histogram -> padded scan -> assign, publishes meta[16..24])
//   - tier2 (ws >= +40MB): sd/wd tcast folded INTO front (own sdT/wdT bufs),
//     eo moves to the wguT region (free after gu). 5 launches total:
//     front -> assign1 -> gu -> down -> combine.
//   - tier1 (smaller ws): R11 structure minus zmeta (6 launches).
// GEMM bodies/epilogues frozen (proven).

typedef unsigned short u16;
typedef unsigned int   u32;
typedef __bf16 bf16x8 __attribute__((ext_vector_type(8)));
typedef float  f32x4  __attribute__((ext_vector_type(4)));

#define T_TOK 2048
#define HDIM  2048
#define IDIM  1024
#define NEXP  8
#define ISDIM 2048
#define MAXROWS   5760   // fused path: 192-padded, worst 4096+8*191=5624 -> 30 tiles
#define MAXROWS_FB 5120  // fallback path: 128-padded

__device__ __forceinline__ u16 f2bf(float f) {
  u32 x = __float_as_uint(f);
  return (u16)((x + 0x7FFFu + ((x >> 16) & 1u)) >> 16);
}
__device__ __forceinline__ float bf2f(u16 v) { return __uint_as_float(((u32)v) << 16); }

#define GLL(g, l)                                                              \
  __builtin_amdgcn_global_load_lds(                                            \
      (const __attribute__((address_space(1))) void*)(g),                      \
      (__attribute__((address_space(3))) void*)(l), 16, 0, 0)

// ---------------- init (fallback path) ----------------
__global__ void init_kernel(int* __restrict__ perm, int* __restrict__ meta,
                            int* __restrict__ zrow) {
  int idx = blockIdx.x * 256 + threadIdx.x;
  if (idx < 8192) perm[idx] = -1;
  if (idx < 32) meta[idx] = 0;
  if (idx < 1024) zrow[idx] = 0;
}

// ---------------- transpose-cast tile core: 128 rows x 64 cols ----------------
// in fp32 [*][C], out bf16 [colmap][R]; ilv: out-row = (c>>4)*32+(c&15)+uoff
__device__ __forceinline__ void tcast_tile2(const float* __restrict__ in,
                                            u16* __restrict__ out, int R, int C,
                                            int r0, int c0, int ilv, int uoff) {
  __shared__ float tile[128 * 65];
  int t = threadIdx.x;
  int i = t >> 4, j4 = t & 15;
#pragma unroll
  for (int ii = 0; ii < 8; ii++) {
    int r = i + ii * 16;  // 0..127
    float4 v = *(const float4*)(in + (long)(r0 + r) * C + c0 + j4 * 4);
    tile[r * 65 + j4 * 4 + 0] = v.x;
    tile[r * 65 + j4 * 4 + 1] = v.y;
    tile[r * 65 + j4 * 4 + 2] = v.z;
    tile[r * 65 + j4 * 4 + 3] = v.w;
  }
  __syncthreads();
  const int cc = t >> 4, ch = t & 15;  // cc 0..15, chunk ch 0..15
  const int rr = ch * 8;               // u16 offset 0..120
#pragma unroll
  for (int ph = 0; ph < 4; ph++) {
    int c = cc + ph * 16;  // dest row 0..63
    u16 e[8];
#pragma unroll
    for (int u = 0; u < 8; u++) e[u] = f2bf(tile[(rr + u) * 65 + c]);
    uint4 w;
    w.x = (u32)e[0] | ((u32)e[1] << 16);
    w.y = (u32)e[2] | ((u32)e[3] << 16);
    w.z = (u32)e[4] | ((u32)e[5] << 16);
    w.w = (u32)e[6] | ((u32)e[7] << 16);
    int cg = c0 + c;
    int orow = ilv ? ((cg >> 4) << 5) + (cg & 15) + uoff : cg;
    *(uint4*)(out + (long)orow * R + r0 + rr) = w;
  }
}

// ---------------- gate core ----------------
// ZERO_OUT: also zero out[] (fallback path). ATOMIC: meta[e] counting
// (fallback path; fused tiers count in assign1 instead).
template <bool ZERO_OUT, bool ATOMIC>
__device__ __forceinline__ void gate_core(const float* __restrict__ x,
                                          const float* __restrict__ gw,
                                          u16* __restrict__ xb,
                                          float* __restrict__ outz,
                                          float* __restrict__ topw,
                                          int* __restrict__ topi,
                                          int* __restrict__ meta, int t) {
  const int tid = threadIdx.x;
  const long o = (long)t * HDIM + tid * 8;
  float4 a = *(const float4*)(x + o);
  float4 b = *(const float4*)(x + o + 4);
  if constexpr (ZERO_OUT) {
    float4 z = {0.f, 0.f, 0.f, 0.f};
    *(float4*)(outz + o) = z;
    *(float4*)(outz + o + 4) = z;
  }
  uint4 w;
  w.x = (u32)f2bf(a.x) | ((u32)f2bf(a.y) << 16);
  w.y = (u32)f2bf(a.z) | ((u32)f2bf(a.w) << 16);
  w.z = (u32)f2bf(b.x) | ((u32)f2bf(b.y) << 16);
  w.w = (u32)f2bf(b.z) | ((u32)f2bf(b.w) << 16);
  *(uint4*)(xb + o) = w;
  float acc[NEXP];
#pragma unroll
  for (int e = 0; e < NEXP; e++) {
    const float* gr = gw + e * HDIM + tid * 8;
    float4 wa = *(const float4*)gr;
    float4 wb = *(const float4*)(gr + 4);
    acc[e] = a.x * wa.x + a.y * wa.y + a.z * wa.z + a.w * wa.w +
             b.x * wb.x + b.y * wb.y + b.z * wb.z + b.w * wb.w;
  }
#pragma unroll
  for (int off = 32; off; off >>= 1)
#pragma unroll
    for (int e = 0; e < NEXP; e++) acc[e] += __shfl_down(acc[e], off, 64);
  __shared__ float red[4][NEXP];
  if ((tid & 63) == 0) {
#pragma unroll
    for (int e = 0; e < NEXP; e++) red[tid >> 6][e] = acc[e];
  }
  __syncthreads();
  if (tid == 0) {
    float s[NEXP];
#pragma unroll
    for (int e = 0; e < NEXP; e++) s[e] = red[0][e] + red[1][e] + red[2][e] + red[3][e];
    int i0 = 0;
#pragma unroll
    for (int e = 1; e < NEXP; e++)
      if (s[e] > s[i0]) i0 = e;
    int i1 = -1;
#pragma unroll
    for (int e = 0; e < NEXP; e++) {
      if (e == i0) continue;
      if (i1 < 0 || s[e] > s[i1]) i1 = e;
    }
    float w0 = 1.f / (1.f + __expf(s[i1] - s[i0]));  // softmax->top2->renorm
    topw[t * 2 + 0] = w0;
    topw[t * 2 + 1] = 1.f - w0;
    topi[t * 2 + 0] = i0;
    topi[t * 2 + 1] = i1;
    if constexpr (ATOMIC) {
      atomicAdd(meta + i0, 1);
      atomicAdd(meta + i1, 1);
    }
  }
}

// ---- front: gate (2048) + wgu (4096) + sgsu (1024) + init (33)
//      [+ tier2: sd (512) + wd (2048)] — grid 7201 (tier1) or 9761 (tier2) ----
__global__ __launch_bounds__(256) void front_kernel(
    const float* __restrict__ x, const float* __restrict__ gw,
    const float* __restrict__ wg, const float* __restrict__ wu,
    const float* __restrict__ sg, const float* __restrict__ su,
    const float* __restrict__ sd, const float* __restrict__ wd,
    u16* __restrict__ xb, float* __restrict__ topw, int* __restrict__ topi,
    u16* __restrict__ wguT, u16* __restrict__ sgsuT, u16* __restrict__ sdT,
    u16* __restrict__ wdT, int* __restrict__ perm, int* __restrict__ zrow) {
  int b = blockIdx.x;
  if (b < 2048) {  // gate part (no atomics, no out-zeroing on fused tiers)
    gate_core<false, false>(x, gw, xb, nullptr, topw, topi, nullptr, b);
    return;
  }
  b -= 2048;
  if (b < 4096) {  // wgu: z<8 wg / z>=8 wu, 256 blocks per z (y16 x16)
    int z = b >> 8, rem = b & 255, y = rem >> 4, xk = rem & 15;
    int isU = z >= 8 ? 1 : 0;
    int e = isU ? z - 8 : z;
    const float* in = (isU ? wu : wg) + (long)e * HDIM * IDIM;
    u16* o = wguT + (long)e * 2 * IDIM * HDIM;
    tcast_tile2(in, o, HDIM, IDIM, y * 128, xk * 64, 1, isU ? 16 : 0);
    return;
  }
  b -= 4096;
  if (b < 1024) {  // sgsu: 512 blocks per z (y16 x32)
    int z = b >> 9, rem = b & 511, y = rem >> 5, xk = rem & 31;
    const float* in = z ? su : sg;
    tcast_tile2(in, sgsuT, HDIM, ISDIM, y * 128, xk * 64, 1, z ? 16 : 0);
    return;
  }
  b -= 1024;
  if (b < 33) {  // init part
    int idx = b * 256 + threadIdx.x;
    if (idx < 8192) perm[idx] = -1;
    if (b == 32) {
#pragma unroll
      for (int k = 0; k < 4; k++) zrow[threadIdx.x * 4 + k] = 0;
    }
    return;
  }
  b -= 33;  // tier2-only back sections
  if (b < 512) {  // sd [IS][H] -> sdT [H][IS]: y16 x32
    int y = b >> 5, xk = b & 31;
    tcast_tile2(sd, sdT, ISDIM, HDIM, y * 128, xk * 64, 0, 0);
    return;
  }
  b -= 512;  // wd [e][I][H] -> wdT [e][H][I], 256 per z (y8 x32)
  int z = b >> 8, rem = b & 255, y = rem >> 5, xk = rem & 31;
  tcast_tile2(wd + (long)z * IDIM * HDIM, wdT + (long)z * HDIM * IDIM, IDIM, HDIM,
              y * 128, xk * 64, 0, 0);
}

// ---- assign1: single block, 1024 threads. Histogram topi -> padded scan ->
// publish meta[16..24] -> assign perm/tokrow. Replaces zmeta+assign. ----
__global__ __launch_bounds__(1024) void assign1_kernel(const int* __restrict__ topi,
                                                       int* __restrict__ meta,
                                                       int* __restrict__ perm,
                                                       int* __restrict__ tokrow,
                                                       int pad) {
  __shared__ int cnt[NEXP], offs[9], cur[NEXP];
  const int tid = threadIdx.x;
  if (tid < NEXP) {
    cnt[tid] = 0;
    cur[tid] = 0;
  }
  __syncthreads();
  int e[4];
#pragma unroll
  for (int j = 0; j < 4; j++) {
    e[j] = topi[tid * 4 + j];
    atomicAdd(&cnt[e[j]], 1);
  }
  __syncthreads();
  if (tid == 0) {
    int o = 0;
    offs[0] = 0;
#pragma unroll
    for (int ee = 0; ee < NEXP; ee++) {
      o += ((cnt[ee] + pad - 1) / pad) * pad;
      offs[ee + 1] = o;
    }
  }
  __syncthreads();
  if (tid < 9) meta[16 + tid] = offs[tid];
#pragma unroll
  for (int j = 0; j < 4; j++) {
    int idx = tid * 4 + j;
    int pos = atomicAdd(&cur[e[j]], 1);
    int row = offs[e[j]] + pos;
    perm[row] = idx;
    tokrow[idx] = row;
  }
}

// ---- back: sd (512 blk) + wd (2048 blk) plain tcast (tier1 only) ----
__global__ __launch_bounds__(256) void tcast_back(const float* __restrict__ sd,
                                                  const float* __restrict__ wd,
                                                  u16* __restrict__ sdT,
                                                  u16* __restrict__ wdT) {
  int b = blockIdx.x;
  if (b < 512) {
    int y = b >> 5, xk = b & 31;
    tcast_tile2(sd, sdT, ISDIM, HDIM, y * 128, xk * 64, 0, 0);
  } else {
    int b2 = b - 512;
    int z = b2 >> 8, rem = b2 & 255, y = rem >> 5, xk = rem & 31;
    tcast_tile2(wd + (long)z * IDIM * HDIM, wdT + (long)z * HDIM * IDIM, IDIM, HDIM,
                y * 128, xk * 64, 0, 0);
  }
}

// ---------------- gate (fallback path: zeroes out, atomics) ----------------
__global__ __launch_bounds__(256) void gate_kernel(
    const float* __restrict__ x, const float* __restrict__ gw,
    u16* __restrict__ xb, float* __restrict__ outz,
    float* __restrict__ topw, int* __restrict__ topi, int* __restrict__ meta) {
  gate_core<true, true>(x, gw, xb, outz, topw, topi, meta, blockIdx.x);
}

// ---------------- scan (fallback path) ----------------
__global__ void scan_kernel(int* __restrict__ meta, int pad) {
  if (threadIdx.x == 0 && blockIdx.x == 0) {
    int o = 0;
    meta[16] = 0;
#pragma unroll
    for (int e = 0; e < NEXP; e++) {
      o += ((meta[e] + pad - 1) / pad) * pad;
      meta[17 + e] = o;
    }
  }
}

// ---------------- assign (fallback path; reads meta[16..]) ----------------
__global__ void assign_kernel(const int* __restrict__ topi, int* __restrict__ meta,
                              int* __restrict__ perm, int* __restrict__ tokrow) {
  __shared__ int offs[9];
  if (threadIdx.x < 9) offs[threadIdx.x] = meta[16 + threadIdx.x];
  __syncthreads();
  int idx = blockIdx.x * 256 + threadIdx.x;  // < 4096
  int e = topi[idx];
  int pos = atomicAdd(meta + 8 + e, 1);
  int row = offs[e] + pos;
  perm[row] = idx;
  tokrow[idx] = row;
}

// ---------------- legacy blockIdx-based tcast (fallback path) ----------------
__global__ __launch_bounds__(256) void tcast_kernel(const float* __restrict__ in,
                                                    u16* __restrict__ out, int R, int C,
                                                    long inz, long outz) {
  tcast_tile2(in + (long)blockIdx.z * inz, out + (long)blockIdx.z * outz, R, C,
              blockIdx.y * 128, blockIdx.x * 64, 0, 0);
}

// ---------------- silu-mul in place (fallback path) ----------------
template <int HALF8>  // half-width / 8
__device__ __forceinline__ void silu_do(u16* __restrict__ buf, long i) {
  long r = i / HALF8, c = i % HALF8;
  u16* g = buf + r * (long)HALF8 * 16 + c * 8;
  uint4 gv = *(const uint4*)g;
  uint4 uv = *(const uint4*)(g + HALF8 * 8);
  const u32* gp = &gv.x;
  const u32* up = &uv.x;
  uint4 w;
  u32* wp = &w.x;
#pragma unroll
  for (int j = 0; j < 4; j++) {
    float g0 = bf2f((u16)(gp[j] & 0xFFFF)), g1 = bf2f((u16)(gp[j] >> 16));
    float u0 = bf2f((u16)(up[j] & 0xFFFF)), u1 = bf2f((u16)(up[j] >> 16));
    float r0 = g0 / (1.f + __expf(-g0)) * u0;
    float r1 = g1 / (1.f + __expf(-g1)) * u1;
    wp[j] = (u32)f2bf(r0) | ((u32)f2bf(r1) << 16);
  }
  *(uint4*)g = w;
}
template <int HALF8>
__global__ void silu_kernel(u16* __restrict__ buf) {
  long i = (long)blockIdx.x * 256 + threadIdx.x;
  silu_do<HALF8>(buf, i);
}

// ================= phase-interleaved GEMM body (R3, proven) =================
// BM = MI*32 x BN=256, BK=32, 512 threads = 8 waves (2M x 4N), wave (MI*16)x64.
// LDS: 3 buffers x [A 256x32 | B 256x32] = 3x16384 u16 = 96KB. Stage tile t+2
// during tile t (4 GLL: A0,A1 ph1; B0,B1 ph2); end-of-tile s_waitcnt vmcnt(4)
// (outstanding = t+2's 4 -> t+1's landed, in-order); s_barrier publishes.
// Chunk-XOR swizzle slot = kc ^ ((row>>1)&3): ds_read_b128 conflict-free.
// EPI: 0 = plain bf16, 1 = plain fp32, 2 = silu-pair bf16 (B cols interleaved
// g|u at 16-granularity; acc[ni],acc[ni+1] = g,u of same 16 logical cols).
template <int EPI, int MI, bool PERMA, bool SEGB>
__device__ __forceinline__ void gemm_body3(
    int mt, int nt, u16* lds, const u16* __restrict__ A, long lda,
    const u16* __restrict__ B, long ldbz, int K, u16* __restrict__ Cb,
    float* __restrict__ Cf, long ldc, const int* __restrict__ offp,
    const int* __restrict__ perm, const u16* __restrict__ zrow) {
  const int row0 = mt * (MI * 32);
  if constexpr (SEGB) {
    if (row0 >= offp[8]) return;
    int e = 0;
    while (offp[e + 1] <= row0) ++e;
    B += (long)e * ldbz;
  }
  const int tid = threadIdx.x;

  // ---- staging sources (pre-swizzled chunk; LDS dest linear) ----
  const int ra = tid >> 2, sa = tid & 3;
  const int swz0 = (sa ^ ((ra >> 1) & 3)) * 8;
  const u16 *gA0, *gA1;
  if constexpr (PERMA) {
    int p0 = perm[row0 + ra];
    int p1 = perm[row0 + 128 + ra];
    gA0 = ((p0 < 0) ? zrow : A + (long)(p0 >> 1) * lda) + swz0;
    gA1 = ((p1 < 0) ? zrow : A + (long)(p1 >> 1) * lda) + swz0;
  } else {
    gA0 = A + (long)(row0 + ra) * lda + swz0;
    gA1 = A + (long)(row0 + 128 + ra) * lda + swz0;
  }
  const u16* gB0 = B + (long)(nt * 256 + ra) * K + swz0;
  const u16* gB1 = B + (long)(nt * 256 + 128 + ra) * K + swz0;

  // ---- fragment read offsets (u16 elements within one buffer) ----
  const int lane = tid & 63, w = tid >> 6;
  const int wm = (w >> 2) * (MI * 16), wn = (w & 3) * 64;
  const int lrow = lane & 15, kc = lane >> 4;
  int offA[MI], offB[4];
#pragma unroll
  for (int i = 0; i < MI; i++) {
    int r = wm + i * 16 + lrow;
    offA[i] = r * 32 + ((kc ^ ((r >> 1) & 3)) << 3);
  }
#pragma unroll
  for (int i = 0; i < 4; i++) {
    int r = wn + i * 16 + lrow;
    offB[i] = 8192 + r * 32 + ((kc ^ ((r >> 1) & 3)) << 3);
  }

  f32x4 acc[MI][4];
#pragma unroll
  for (int i = 0; i < MI; i++)
#pragma unroll
    for (int j = 0; j < 4; j++) acc[i][j] = f32x4{0.f, 0.f, 0.f, 0.f};

  const int nk = K >> 5;
  // prologue: stage tiles 0 and 1 (8 loads), wait for tile 0 (leave tile 1's 4)
  {
    u16* b0 = lds;
    GLL(gA0, b0 + tid * 8);
    GLL(gA1, b0 + 4096 + tid * 8);
    GLL(gB0, b0 + 8192 + tid * 8);
    GLL(gB1, b0 + 12288 + tid * 8);
    u16* b1 = lds + 16384;
    GLL(gA0 + 32, b1 + tid * 8);
    GLL(gA1 + 32, b1 + 4096 + tid * 8);
    GLL(gB0 + 32, b1 + 8192 + tid * 8);
    GLL(gB1 + 32, b1 + 12288 + tid * 8);
  }
  asm volatile("s_waitcnt vmcnt(4)" ::: "memory");
  asm volatile("s_barrier" ::: "memory");

  constexpr int MH = MI / 2;
  int cur = 0, stg = 2;
  for (int t = 0; t < nk; ++t) {
    int t2 = t + 2;
    if (t2 >= nk) t2 -= nk;  // tail: wrap-stage into dead buffer (drained at end)
    const int kk2 = t2 * 32;
    u16* buf = lds + cur * 16384;
    u16* sb = lds + stg * 16384;

    // ---- phase 1: read A[mi<MH] + B; stage A(t+2); MFMA quad 1 ----
    bf16x8 af[MH], bfv[4];
#pragma unroll
    for (int i = 0; i < MH; i++) af[i] = *(const bf16x8*)(buf + offA[i]);
#pragma unroll
    for (int i = 0; i < 4; i++) bfv[i] = *(const bf16x8*)(buf + offB[i]);
    GLL(gA0 + kk2, sb + tid * 8);
    GLL(gA1 + kk2, sb + 4096 + tid * 8);
    asm volatile("s_barrier" ::: "memory");
    __builtin_amdgcn_s_setprio(1);
#pragma unroll
    for (int mi = 0; mi < MH; mi++)
#pragma unroll
      for (int ni = 0; ni < 4; ni++)
        acc[mi][ni] = __builtin_amdgcn_mfma_f32_16x16x32_bf16(af[mi], bfv[ni],
                                                              acc[mi][ni], 0, 0, 0);
    __builtin_amdgcn_s_setprio(0);
    asm volatile("s_barrier" ::: "memory");

    // ---- phase 2: read A[mi>=MH]; stage B(t+2); MFMA quad 2 ----
    bf16x8 ag[MI - MH];
#pragma unroll
    for (int i = 0; i < MI - MH; i++) ag[i] = *(const bf16x8*)(buf + offA[MH + i]);
    GLL(gB0 + kk2, sb + 8192 + tid * 8);
    GLL(gB1 + kk2, sb + 12288 + tid * 8);
    asm volatile("s_barrier" ::: "memory");
    __builtin_amdgcn_s_setprio(1);
#pragma unroll
    for (int mi = 0; mi < MI - MH; mi++)
#pragma unroll
      for (int ni = 0; ni < 4; ni++)
        acc[MH + mi][ni] = __builtin_amdgcn_mfma_f32_16x16x32_bf16(
            ag[mi], bfv[ni], acc[MH + mi][ni], 0, 0, 0);
    __builtin_amdgcn_s_setprio(0);
    asm volatile("s_waitcnt vmcnt(4)" ::: "memory");
    asm volatile("s_barrier" ::: "memory");
    cur = (cur == 2) ? 0 : cur + 1;
    stg = (stg == 2) ? 0 : stg + 1;
  }
  asm volatile("s_waitcnt vmcnt(0)" ::: "memory");

  // C/D layout: col = lane&15, row = (lane>>4)*4 + reg   [measured m89/m91]
  const int crow = row0 + wm + ((lane >> 4) << 2);
#pragma unroll
  for (int mi = 0; mi < MI; mi++) {
    if constexpr (EPI == 2) {
      // logical col = nt*128 + wn/2 + nh*16 + (lane&15); pair (2nh, 2nh+1)=(g,u)
      const int ccl = nt * 128 + (wn >> 1) + (lane & 15);
#pragma unroll
      for (int nh = 0; nh < 2; nh++) {
        f32x4 g = acc[mi][nh * 2], u = acc[mi][nh * 2 + 1];
#pragma unroll
        for (int r = 0; r < 4; r++) {
          float gg = g[r];
          float h = gg / (1.f + __expf(-gg)) * u[r];
          Cb[(long)(crow + mi * 16 + r) * ldc + ccl + nh * 16] = f2bf(h);
        }
      }
    } else {
      const int ccol = nt * 256 + wn + (lane & 15);
#pragma unroll
      for (int ni = 0; ni < 4; ni++) {
#pragma unroll
        for (int r = 0; r < 4; r++) {
          int row = crow + mi * 16 + r;
          int col = ccol + ni * 16;
          float v = acc[mi][ni][r];
          if constexpr (EPI == 0) {
            Cb[(long)row * ldc + col] = f2bf(v);
          } else {
            Cf[(long)row * ldc + col] = v;
          }
        }
      }
    }
  }
}

// ---- fused [shared gu (128, BM=256) | routed gu (240, BM=192)], silu epilogue ----
__global__ __launch_bounds__(512, 2) void gemm_gu_fused(
    const u16* __restrict__ xb, const u16* __restrict__ wguT,
    const u16* __restrict__ sgsuT, u16* __restrict__ gur, u16* __restrict__ gus,
    const int* __restrict__ offp, const int* __restrict__ perm,
    const u16* __restrict__ zrow) {
  __shared__ __align__(16) u16 lds3[49152];
  int bid = blockIdx.x;
  if (bid < 128) {
    gemm_body3<2, 8, false, false>(bid >> 4, bid & 15, lds3, xb, HDIM, sgsuT, 0, HDIM,
                                   gus, nullptr, ISDIM, nullptr, nullptr, nullptr);
  } else {
    int b = bid - 128;  // mt 0..29, nt 0..7
    gemm_body3<2, 6, true, true>(b >> 3, b & 7, lds3, xb, HDIM, wguT,
                                 (long)2 * IDIM * HDIM, HDIM, gur, nullptr, IDIM,
                                 offp, perm, zrow);
  }
}

// ---- fused [shared down fp32 (64, BM=256) | routed down bf16->eo (240, BM=192)] ----
__global__ __launch_bounds__(512, 2) void gemm_down_plain(
    const u16* __restrict__ gus, const u16* __restrict__ sdT,
    const u16* __restrict__ gur, const u16* __restrict__ wdT, float* __restrict__ out,
    u16* __restrict__ eo, const int* __restrict__ offp) {
  __shared__ __align__(16) u16 lds3[49152];
  int bid = blockIdx.x;
  if (bid < 64) {
    gemm_body3<1, 8, false, false>(bid >> 3, bid & 7, lds3, gus, ISDIM, sdT, 0,
                                   ISDIM, nullptr, out, HDIM, nullptr, nullptr, nullptr);
  } else {
    int b = bid - 64;  // mt 0..29, nt 0..7
    gemm_body3<0, 6, false, true>(b >> 3, b & 7, lds3, gur, IDIM, wdT,
                                  (long)HDIM * IDIM, IDIM, eo, nullptr, HDIM, offp,
                                  nullptr, nullptr);
  }
}

// ---- combine: out[t] += w0*eo[r0] + w1*eo[r1] ----
__global__ __launch_bounds__(256) void combine_kernel(float* __restrict__ out,
                                                      const u16* __restrict__ eo,
                                                      const int* __restrict__ tokrow,
                                                      const float* __restrict__ topw) {
  const int t = blockIdx.x, tid = threadIdx.x;
  const long o = (long)t * HDIM + tid * 8;
  const int r0 = tokrow[t * 2], r1 = tokrow[t * 2 + 1];
  const float w0 = topw[t * 2], w1 = topw[t * 2 + 1];
  float4 a = *(const float4*)(out + o);
  float4 b = *(const float4*)(out + o + 4);
  uint4 e0 = *(const uint4*)(eo + (long)r0 * HDIM + tid * 8);
  uint4 e1 = *(const uint4*)(eo + (long)r1 * HDIM + tid * 8);
  const u32* p0 = &e0.x;
  const u32* p1 = &e1.x;
  float r[8] = {a.x, a.y, a.z, a.w, b.x, b.y, b.z, b.w};
#pragma unroll
  for (int j = 0; j < 4; j++) {
    r[j * 2 + 0] += w0 * bf2f((u16)(p0[j] & 0xFFFF)) + w1 * bf2f((u16)(p1[j] & 0xFFFF));
    r[j * 2 + 1] += w0 * bf2f((u16)(p0[j] >> 16)) + w1 * bf2f((u16)(p1[j] >> 16));
  }
  float4 oa = {r[0], r[1], r[2], r[3]};
  float4 ob = {r[4], r[5], r[6], r[7]};
  *(float4*)(out + o) = oa;
  *(float4*)(out + o + 4) = ob;
}

// ======== legacy 128x128 body (fallback path only, 128-padded segments) ========
template <int CMODE, bool PERMA, bool SEGB>
__device__ __forceinline__ void gemm_body(
    int mt, int nt, u16* ldsA, u16* ldsB, const u16* __restrict__ A, long lda,
    const u16* __restrict__ B, long ldbz, int K, u16* __restrict__ Cb,
    float* __restrict__ Cf, long ldc, const int* __restrict__ offp,
    const int* __restrict__ perm, const float* __restrict__ topw,
    const u16* __restrict__ zrow) {
  const int row0 = mt * 128;
  if constexpr (SEGB) {
    if (row0 >= offp[8]) return;
    int e = 0;
    while (offp[e + 1] <= row0) ++e;
    B += (long)e * ldbz;
  }
  const int tid = threadIdx.x;
  const u16* gA[4];
  const u16* gB[4];
  u16 *lA[4], *lB[4];
#pragma unroll
  for (int j = 0; j < 4; j++) {
    int c = tid + 256 * j;
    int r = c >> 3, s = c & 7;
    int gk = (s ^ (r & 7)) * 8;
    const u16* arow;
    if constexpr (PERMA) {
      int p = perm[row0 + r];
      arow = (p < 0) ? zrow : A + (long)(p >> 1) * lda;
    } else {
      arow = A + (long)(row0 + r) * lda;
    }
    gA[j] = arow + gk;
    gB[j] = B + (long)(nt * 128 + r) * K + gk;
    lA[j] = ldsA + c * 8;
    lB[j] = ldsB + c * 8;
  }
  const int lane = tid & 63, wave = tid >> 6;
  const int wm = (wave & 1) * 64, wn = (wave >> 1) * 64;
  const int lrow = lane & 15;
  const int kchunk = lane >> 4;
  const int rsw = lrow & 7;

  f32x4 acc[4][4];
#pragma unroll
  for (int i = 0; i < 4; i++)
#pragma unroll
    for (int j = 0; j < 4; j++) acc[i][j] = f32x4{0.f, 0.f, 0.f, 0.f};

  const int nk = K >> 6;
  for (int kt = 0; kt < nk; ++kt) {
    const int kk = kt * 64;
#pragma unroll
    for (int j = 0; j < 4; j++) {
      GLL(gA[j] + kk, lA[j]);
      GLL(gB[j] + kk, lB[j]);
    }
    __syncthreads();
#pragma unroll
    for (int half = 0; half < 2; half++) {
      const int slot = (kchunk + half * 4) ^ rsw;
      bf16x8 af[4], bfv[4];
#pragma unroll
      for (int mi = 0; mi < 4; mi++)
        af[mi] = *(const bf16x8*)(ldsA + (wm + lrow + mi * 16) * 64 + slot * 8);
#pragma unroll
      for (int ni = 0; ni < 4; ni++)
        bfv[ni] = *(const bf16x8*)(ldsB + (wn + lrow + ni * 16) * 64 + slot * 8);
#pragma unroll
      for (int mi = 0; mi < 4; mi++)
#pragma unroll
        for (int ni = 0; ni < 4; ni++)
          acc[mi][ni] = __builtin_amdgcn_mfma_f32_16x16x32_bf16(af[mi], bfv[ni],
                                                                acc[mi][ni], 0, 0, 0);
    }
    __syncthreads();
  }

  const int crow = row0 + wm + ((lane >> 4) << 2);
  const int ccol = nt * 128 + wn + (lane & 15);
#pragma unroll
  for (int mi = 0; mi < 4; mi++) {
#pragma unroll
    for (int ni = 0; ni < 4; ni++) {
#pragma unroll
      for (int r = 0; r < 4; r++) {
        int row = crow + mi * 16 + r;
        int col = ccol + ni * 16;
        float v = acc[mi][ni][r];
        if constexpr (CMODE == 0) {
          Cb[(long)row * ldc + col] = f2bf(v);
        } else if constexpr (CMODE == 1) {
          Cf[(long)row * ldc + col] = v;
        } else if constexpr (CMODE == 2) {
          int p = perm[row];
          if (p >= 0) atomicAdd(Cf + (long)(p >> 1) * ldc + col, topw[p] * v);
        } else {
          atomicAdd(Cf + (long)row * ldc + col, v);
        }
      }
    }
  }
}

// ---- fallback kernels (small ws): atomic design, 128-padded ----
__global__ __launch_bounds__(256) void gemm_routed_gu(
    const u16* __restrict__ xb, const u16* __restrict__ wT, u16* __restrict__ Cb,
    const int* __restrict__ offp, const int* __restrict__ perm,
    const u16* __restrict__ zrow) {
  __shared__ __align__(16) u16 ldsA[8192], ldsB[8192];
  gemm_body<0, true, true>(blockIdx.y, blockIdx.x, ldsA, ldsB, xb, HDIM, wT,
                           (long)IDIM * HDIM, HDIM, Cb, nullptr, 2 * IDIM, offp, perm,
                           nullptr, zrow);
}
__global__ __launch_bounds__(256) void gemm_shared_gu(const u16* __restrict__ xb,
                                                      const u16* __restrict__ sgsuT,
                                                      u16* __restrict__ gus) {
  __shared__ __align__(16) u16 ldsA[8192], ldsB[8192];
  gemm_body<0, false, false>(blockIdx.y, blockIdx.x, ldsA, ldsB, xb, HDIM, sgsuT, 0, HDIM,
                             gus, nullptr, 2 * ISDIM, nullptr, nullptr, nullptr, nullptr);
}
__global__ __launch_bounds__(256) void gemm_down_atomic(
    const u16* __restrict__ gus, const u16* __restrict__ sdT,
    const u16* __restrict__ gur, const u16* __restrict__ wdT, float* __restrict__ out,
    const int* __restrict__ offp, const int* __restrict__ perm,
    const float* __restrict__ topw) {
  __shared__ __align__(16) u16 ldsA[8192], ldsB[8192];
  int bid = blockIdx.x;
  if (bid < 256) {
    gemm_body<3, false, false>(bid / 16, bid % 16, ldsA, ldsB, gus, 2 * ISDIM, sdT, 0,
                               ISDIM, nullptr, out, HDIM, nullptr, nullptr, nullptr,
                               nullptr);
  } else {
    int b = bid - 256;
    gemm_body<2, false, true>(b / 16, b % 16, ldsA, ldsB, gur, 2 * IDIM, wdT,
                              (long)HDIM * IDIM, IDIM, nullptr, out, HDIM, offp, perm,
                              topw, nullptr);
  }
}

extern "C" void kernel_launch(void* const* d_in, const int* in_sizes, int n_in,
                              void* d_out, int out_size, void* d_ws, size_t ws_size,
                              hipStream_t stream) {
  const float* x  = (const float*)d_in[0];
  const float* gw = (const float*)d_in[1];
  const float* wg = (const float*)d_in[2];
  const float* wu = (const float*)d_in[3];
  const float* wd = (const float*)d_in[4];
  const float* sg = (const float*)d_in[5];
  const float* su = (const float*)d_in[6];
  const float* sd = (const float*)d_in[7];
  float* out = (float*)d_out;

  char* ws = (char*)d_ws;
  size_t off = 0;
  auto alloc = [&](size_t b) {
    size_t o = off;
    off += (b + 255) & ~(size_t)255;
    return (void*)(ws + o);
  };
  u16*   xb     = (u16*)alloc((size_t)T_TOK * HDIM * 2);
  u16*   gur    = (u16*)alloc((size_t)MAXROWS * 2 * IDIM * 2);  // fused: hr in [MAXROWS][IDIM]
  u16*   gus    = (u16*)alloc((size_t)T_TOK * 2 * ISDIM * 2);   // fused: hs in [T_TOK][ISDIM]
  float* topw   = (float*)alloc((size_t)T_TOK * 2 * 4);
  int*   topi   = (int*)alloc((size_t)T_TOK * 2 * 4);
  int*   tokrow = (int*)alloc((size_t)T_TOK * 2 * 4);
  int*   perm   = (int*)alloc(8192 * 4);
  int*   meta   = (int*)alloc(64 * 4);
  u16*   zrow   = (u16*)alloc(4096);
  size_t base = off;

  const size_t SZ_WGUT  = (size_t)NEXP * 2 * IDIM * HDIM * 2;  // 64 MiB
  const size_t SZ_SGSUT = (size_t)2 * ISDIM * HDIM * 2;        // 16 MiB
  const size_t SZ_SDT   = (size_t)HDIM * ISDIM * 2;            // 8 MiB
  const size_t SZ_WDT   = (size_t)NEXP * HDIM * IDIM * 2;      // 32 MiB
  const bool fused = ws_size >= base + SZ_WGUT + SZ_SGSUT;
  const bool big   = ws_size >= base + SZ_WGUT + SZ_SGSUT + SZ_SDT + SZ_WDT;

  if (big) {
    // tier2: 5 launches. Separate sdT/wdT; sd/wd tcast inside front; eo in
    // the wguT region (free after gu GEMM).
    u16* wguT  = (u16*)(ws + base);
    u16* sgsuT = (u16*)(ws + base + SZ_WGUT);
    u16* sdT   = (u16*)(ws + base + SZ_WGUT + SZ_SGSUT);
    u16* wdT   = sdT + SZ_SDT / 2;
    u16* eo    = wguT;  // 23.6 MiB into the 64 MiB wgu region
    front_kernel<<<9761, 256, 0, stream>>>(x, gw, wg, wu, sg, su, sd, wd, xb, topw,
                                           topi, wguT, sgsuT, sdT, wdT, perm,
                                           (int*)zrow);
    assign1_kernel<<<1, 1024, 0, stream>>>(topi, meta, perm, tokrow, 192);
    gemm_gu_fused<<<368, 512, 0, stream>>>(xb, wguT, sgsuT, gur, gus, meta + 16, perm,
                                           zrow);
    gemm_down_plain<<<304, 512, 0, stream>>>(gus, sdT, gur, wdT, out, eo, meta + 16);
    combine_kernel<<<T_TOK, 256, 0, stream>>>(out, eo, tokrow, topw);
  } else if (fused) {
    // tier1: 6 launches (R11 structure, zmeta/atomics removed via assign1).
    u16* wguT  = (u16*)(ws + base);
    u16* sgsuT = (u16*)(ws + base + SZ_WGUT);
    u16* sdT   = wguT;                              // reuse after gu gemm
    u16* wdT   = wguT + SZ_SDT / 2;                 // elements
    u16* eo    = wguT + (SZ_SDT + SZ_WDT) / 2;      // 23.6 MiB in 24 MiB tail
    front_kernel<<<7201, 256, 0, stream>>>(x, gw, wg, wu, sg, su, nullptr, nullptr,
                                           xb, topw, topi, wguT, sgsuT, nullptr,
                                           nullptr, perm, (int*)zrow);
    assign1_kernel<<<1, 1024, 0, stream>>>(topi, meta, perm, tokrow, 192);
    gemm_gu_fused<<<368, 512, 0, stream>>>(xb, wguT, sgsuT, gur, gus, meta + 16, perm,
                                           zrow);
    tcast_back<<<2560, 256, 0, stream>>>(sd, wd, sdT, wdT);
    gemm_down_plain<<<304, 512, 0, stream>>>(gus, sdT, gur, wdT, out, eo, meta + 16);
    combine_kernel<<<T_TOK, 256, 0, stream>>>(out, eo, tokrow, topw);
  } else {
    u16* wT    = (u16*)(ws + base);  // 40 MiB region, sequentially reused
    u16* sgsuT = wT;
    u16* sdT   = wT;
    u16* wdT   = wT + SZ_SDT / 2;
    init_kernel<<<32, 256, 0, stream>>>(perm, meta, (int*)zrow);
    gate_kernel<<<T_TOK, 256, 0, stream>>>(x, gw, xb, out, topw, topi, meta);
    scan_kernel<<<1, 64, 0, stream>>>(meta, 128);
    assign_kernel<<<16, 256, 0, stream>>>(topi, meta, perm, tokrow);
    tcast_kernel<<<dim3(IDIM / 64, HDIM / 128, NEXP), 256, 0, stream>>>(
        wg, wT, HDIM, IDIM, (long)HDIM * IDIM, (long)IDIM * HDIM);
    gemm_routed_gu<<<dim3(8, MAXROWS_FB / 128), 256, 0, stream>>>(xb, wT, gur, meta + 16,
                                                                  perm, zrow);
    tcast_kernel<<<dim3(IDIM / 64, HDIM / 128, NEXP), 256, 0, stream>>>(
        wu, wT, HDIM, IDIM, (long)HDIM * IDIM, (long)IDIM * HDIM);
    gemm_routed_gu<<<dim3(8, MAXROWS_FB / 128), 256, 0, stream>>>(
        xb, wT, gur + IDIM, meta + 16, perm, zrow);
    silu_kernel<128><<<(MAXROWS_FB * IDIM / 8) / 256, 256, 0, stream>>>(gur);
    tcast_kernel<<<dim3(ISDIM / 64, HDIM / 128, 1), 256, 0, stream>>>(sg, sgsuT, HDIM,
                                                                      ISDIM, 0, 0);
    tcast_kernel<<<dim3(ISDIM / 64, HDIM / 128, 1), 256, 0, stream>>>(
        su, sgsuT + (size_t)ISDIM * HDIM, HDIM, ISDIM, 0, 0);
    gemm_shared_gu<<<dim3(32, 16), 256, 0, stream>>>(xb, sgsuT, gus);
    silu_kernel<256><<<(T_TOK * ISDIM / 8) / 256, 256, 0, stream>>>(gus);
    tcast_kernel<<<dim3(HDIM / 64, ISDIM / 128, 1), 256, 0, stream>>>(sd, sdT, ISDIM,
                                                                      HDIM, 0, 0);
    tcast_kernel<<<dim3(HDIM / 64, IDIM / 128, NEXP), 256, 0, stream>>>(
        wd, wdT, IDIM, HDIM, (long)IDIM * HDIM, (long)HDIM * IDIM);
    gemm_down_atomic<<<896, 256, 0, stream>>>(gus, sdT, gur, wdT, out, meta + 16, perm,
                                              topw);
  }
}